// Round 8
// baseline (217.032 us; speedup 1.0000x reference)
//
#include <hip/hip_runtime.h>

#define L 256
#define BATCH 512
#define CIN 32
#define HIDN 128
#define OUTN 512

typedef _Float16 f16x8 __attribute__((ext_vector_type(8)));
typedef float f32x4 __attribute__((ext_vector_type(4)));

#define MFMA16(a, b, c) __builtin_amdgcn_mfma_f32_16x16x32_f16(a, b, c, 0, 0, 0)

static __device__ __forceinline__ unsigned short f16b(_Float16 h) {
    unsigned short u; __builtin_memcpy(&u, &h, 2); return u;
}

// ws layout (bytes):
//   hs     @ 0        (33554432)  fp16 hs[b*32768 + t*128 + j]  (R17: TRANSPOSED)
//   pooled @ 33554432 (262144)    f32 pooled[b*128 + j]
//
// R17: the non-rnn residual has been a constant ~98us all session =
// pool_out_kernel, 4-5x off every roofline axis. Two fixes bundled:
//  1. hs layout [t][b][j] -> [b][t][j]: pool's hs read was 256 chunks of
//     256B at 128-KB stride per block (if it ran at rnn's effective ~370GB/s,
//     32MB = 88us — explains the mystery). Now each pool block reads one
//     sequential 64-KB stream. rnn side is an address-arithmetic change only;
//     stored values bit-identical.
//  2. pool occupancy: split channels 2-way (1024 blocks x 64ch, LDS 36.9KB
//     -> 4 blocks/CU = 4 waves/SIMD, half the per-thread serial work), GEMM
//     tail peeled into its own kernel via a pooled[512][128] f32 intermediate
//     (GEMM numerics identical to the old tail).

// MFMA RNN, fp16 2-term split. 32 blocks (16 batch rows) x 512 thr (8 waves,
// 2/SIMD). R16 structure frozen: 4-chain MFMA STEP, prep fused in prologue,
// ^tq staging swizzle, lgkmcnt(1) barrier guard w/ xB register prefetch.
__global__ __launch_bounds__(512, 1) void rnn_kernel(
    const float* __restrict__ x, const float* __restrict__ h0,
    const float* __restrict__ W_in, const float* __restrict__ b_in,
    const float* __restrict__ W_ih, const float* __restrict__ b_ih,
    const float* __restrict__ W_hh, const float* __restrict__ b_hh,
    unsigned short* __restrict__ hs)
{
    const int tid = threadIdx.x;
    const int bb = blockIdx.x;
    const int lane = tid & 63;
    const int w = tid >> 6;       // wave 0..7
    const int n = lane & 15;      // batch col / B col
    const int q = lane >> 4;      // quad

    __shared__ unsigned short hbuf[2][16][HIDN];     // 8 KB, granule swizzle ^(n&7)
    __shared__ unsigned short xcl[2][16][64][8];     // 32 KB, [buf][tt][granule][c&7]
    __shared__ float wih_s[128][65];                 // 33.3 KB, +1 pad: banks j+m
    __shared__ float win_s[64][32];                  // 8 KB
    __shared__ float bin_s[64];

    // ---- x chunk staging over 512 threads: i=tid+r*512 -> (nn,cc,tq) ----
    float4 xr[4];
    auto issue_chunk = [&](int ci) {
#pragma unroll
        for (int r = 0; r < 4; ++r) {
            int i = tid + r * 512;
            int nn = i >> 7, cc = (i >> 2) & 31, tq = i & 3;
            xr[r] = *(const float4*)(x + (((size_t)bb * 16 + nn) * CIN + cc) * L + ci * 16 + tq * 4);
        }
    };
    auto write_chunk = [&](int buf) {
#pragma unroll
        for (int r = 0; r < 4; ++r) {
            int i = tid + r * 512;
            int nn = i >> 7, cc = (i >> 2) & 31, tq = i & 3;
            int gr = ((cc >> 3) * 16 + (nn ^ ((cc >> 3) << 2))) ^ tq;  // ^tq: bank-spread
            float vv[4] = {xr[r].x, xr[r].y, xr[r].z, xr[r].w};
#pragma unroll
            for (int k = 0; k < 4; ++k)
                xcl[buf][tq * 4 + k][gr][cc & 7] = f16b((_Float16)vv[k]);
        }
    };

    issue_chunk(0);                       // x loads in flight over the prologue

    // ---- stage small weights to LDS ----
    for (int i = tid; i < 128 * 64; i += 512) wih_s[i >> 6][i & 63] = W_ih[i];
    for (int i = tid; i < 64 * 32; i += 512) ((float*)win_s)[i] = W_in[i];
    if (tid < 64) bin_s[tid] = b_in[tid];

    // ---- h0 -> fp16 plane, dbuf 0 (first 256 threads) ----
    if (tid < 256) {
        const int ni = tid >> 4, gi = tid & 15;
        const float4* src = (const float4*)(h0 + ((size_t)bb * 16 + ni) * HIDN + gi * 8);
        float4 a = src[0], b4 = src[1];
        float vv[8] = {a.x, a.y, a.z, a.w, b4.x, b4.y, b4.z, b4.w};
        unsigned short o[8];
#pragma unroll
        for (int i = 0; i < 8; ++i) o[i] = f16b((_Float16)vv[i]);
        *(uint4*)&hbuf[0][ni][(gi ^ (ni & 7)) * 8] = *(uint4*)o;
    }
    __syncthreads();

    // ---- prologue weight derivation (same FLOP order as old prep_kernel;
    //      verified bit-identical in R15/R16) ----
    const int jr = w * 16 + n;
    f16x8 Ah[4], Al[4];
    const float* wrow = W_hh + jr * HIDN;
#pragma unroll
    for (int kc = 0; kc < 4; ++kc) {
        float4 v0 = *(const float4*)(wrow + kc * 32 + q * 8);
        float4 v1 = *(const float4*)(wrow + kc * 32 + q * 8 + 4);
        float vv[8] = {v0.x, v0.y, v0.z, v0.w, v1.x, v1.y, v1.z, v1.w};
        f16x8 H, Lo;
#pragma unroll
        for (int i = 0; i < 8; ++i) {
            _Float16 hi = (_Float16)vv[i];
            H[i] = hi;
            Lo[i] = (_Float16)(vv[i] - (float)hi);
        }
        Ah[kc] = H; Al[kc] = Lo;
    }
    float acc8[8];
#pragma unroll
    for (int i = 0; i < 8; ++i) acc8[i] = 0.f;
    for (int m = 0; m < 64; ++m) {
        float wv = wih_s[jr][m];                 // pad-65 rows: conflict-free
        const float* wc = &win_s[m][q * 8];
#pragma unroll
        for (int i = 0; i < 8; ++i) acc8[i] += wv * wc[i];
    }
    f16x8 Axh, Axl;
#pragma unroll
    for (int i = 0; i < 8; ++i) {
        _Float16 hi = (_Float16)acc8[i];
        Axh[i] = hi;
        Axl[i] = (_Float16)(acc8[i] - (float)hi);
    }
    const int jb0 = w * 16 + q * 4;
    float bs4[4];
#pragma unroll
    for (int r = 0; r < 4; ++r) bs4[r] = b_ih[jb0 + r] + b_hh[jb0 + r];
    for (int m = 0; m < 64; ++m) {
        float bm = bin_s[m];
#pragma unroll
        for (int r = 0; r < 4; ++r) bs4[r] += wih_s[jb0 + r][m] * bm;
    }
    f32x4 bp = (f32x4){bs4[0], bs4[1], bs4[2], bs4[3]};
    const f32x4 zero4 = (f32x4){0.f, 0.f, 0.f, 0.f};

    // ---- finish x staging ----
    write_chunk(0);
    issue_chunk(1);
    __syncthreads();

    // hs TRANSPOSED: [b][t][j] — per step the block writes 16 rows of 256 B at
    // 32-KB stride (full-line write-combined, same as before); pool then reads
    // each b-row as one sequential 64-KB stream.
    unsigned short* hsp = hs + ((size_t)bb * 16 + n) * (L * HIDN) + w * 16 + q * 4;
    const int G = (w * 2 + (q >> 1)) ^ (n & 7);
    const int sw = n & 7;
    const int grs = q * 16 + (n ^ (q << 2));   // this lane's xc granule (pre-swz)

    f16x8 xb0, xb1;
    xb0 = *(const f16x8*)&xcl[0][0][grs][0];   // t=0: tt>>2 = 0

#define STEP(T, IN, OUT, OFF, XCUR, XNEXT)                                     \
    {                                                                          \
        f16x8 Bh0 = *(const f16x8*)&hbuf[IN][n][((0 + q) ^ sw) * 8];           \
        f16x8 Bh1 = *(const f16x8*)&hbuf[IN][n][((4 + q) ^ sw) * 8];           \
        f16x8 Bh2 = *(const f16x8*)&hbuf[IN][n][((8 + q) ^ sw) * 8];           \
        f16x8 Bh3 = *(const f16x8*)&hbuf[IN][n][((12 + q) ^ sw) * 8];          \
        f32x4 c0 = MFMA16(Axh, XCUR, bp);      /* operands all in regs */      \
        f32x4 c2 = MFMA16(Axl, XCUR, zero4);                                   \
        c0 = MFMA16(Ah[0], Bh0, c0);                                           \
        c2 = MFMA16(Al[0], Bh0, c2);                                           \
        f32x4 c1 = MFMA16(Ah[1], Bh1, zero4);                                  \
        f32x4 c3 = MFMA16(Al[1], Bh1, zero4);                                  \
        c0 = MFMA16(Ah[2], Bh2, c0);                                           \
        c2 = MFMA16(Al[2], Bh2, c2);                                           \
        c1 = MFMA16(Ah[3], Bh3, c1);                                           \
        c3 = MFMA16(Al[3], Bh3, c3);                                           \
        if (((T) & 15) == 14 && (T) < L - 16) {                                \
            write_chunk((((T) >> 4) & 1) ^ 1);                                 \
            if ((T) < L - 32) issue_chunk(((T) >> 4) + 2);                     \
        }                                                                      \
        f32x4 acc = (c0 + c1) + (c2 + c3);                                     \
        unsigned short o[4];                                                   \
        for (int r = 0; r < 4; ++r) {                                          \
            float e = __expf(2.f * acc[r]);                                    \
            float hv = 1.f - 2.f * __builtin_amdgcn_rcpf(e + 1.f);             \
            o[r] = f16b((_Float16)hv);                                         \
        }                                                                      \
        uint2 pk; __builtin_memcpy(&pk, o, 8);                                 \
        *(uint2*)&hbuf[OUT][n][G * 8 + (q & 1) * 4] = pk;                      \
        *(uint2*)(hsp + (OFF)) = pk;                                           \
        XNEXT = *(const f16x8*)&xcl[(((T) + 1) >> 4) & 1][((T) + 1) & 15]      \
                                  [grs ^ ((((T) + 1) & 15) >> 2)][0];          \
        asm volatile("" ::: "memory");                                         \
        __builtin_amdgcn_s_waitcnt(0xC17F);  /* lgkmcnt(1): writes drained, */ \
        __builtin_amdgcn_s_barrier();        /* xB prefetch stays in flight */ \
        asm volatile("" ::: "memory");                                         \
    }

    for (int t = 0; t < L; t += 2) {
        STEP(t,     0, 1, 0,     xb0, xb1);
        STEP(t + 1, 1, 0, HIDN,  xb1, xb0);
        hsp += 2 * HIDN;
    }
#undef STEP
}

// Upsample(16->32, align_corners) + hardswish + mean. 1024 blocks =
// (b, j-half), 256 threads = (oy-quarter 4) x (channel 64). LDS 36.9 KB
// (pad 72: keeps uint4 row alignment + spreads staging banks) -> 4 blocks/CU
// = 4 waves/SIMD (old: 2). hs read is one sequential 32-KB stream per block.
__global__ __launch_bounds__(256) void pool_kernel(
    const unsigned short* __restrict__ hs, float* __restrict__ pooled)
{
    const int b = blockIdx.x >> 1, jh = blockIdx.x & 1;
    const int tid = threadIdx.x;
    __shared__ unsigned short m[L][72];     // [t][j-local], pad 72
    __shared__ float ps[4][64];

    const unsigned short* src = hs + (size_t)b * (L * HIDN) + jh * 64;
#pragma unroll
    for (int it = 0; it < 8; ++it) {
        int i = tid + it * 256;             // 256 t x 8 j-octets
        int t = i >> 3, joc = i & 7;
        *(uint4*)&m[t][joc * 8] = *(const uint4*)(src + t * HIDN + joc * 8);
    }
    __syncthreads();

    const int jo = tid & 63, oq = tid >> 6;
    float acc = 0.f;
    for (int oy = oq * 8; oy < oq * 8 + 8; ++oy) {
        float ysf = oy * (15.f / 31.f);
        int y0 = (int)ysf; float wy = ysf - (float)y0; int y1 = min(y0 + 1, 15);
        float rb[16];
#pragma unroll
        for (int sx = 0; sx < 16; ++sx) {
            float v0 = (float)*(const _Float16*)&m[y0 * 16 + sx][jo];
            float v1 = (float)*(const _Float16*)&m[y1 * 16 + sx][jo];
            rb[sx] = v0 + wy * (v1 - v0);
        }
#pragma unroll
        for (int ox = 0; ox < 32; ++ox) {
            float xsf = ox * (15.f / 31.f);
            int x0 = (int)xsf; float wx = xsf - (float)x0; int x1 = min(x0 + 1, 15);
            float v = rb[x0] + wx * (rb[x1] - rb[x0]);
            float t6 = fminf(fmaxf(v + 3.f, 0.f), 6.f);
            acc += v * t6;
        }
    }
    ps[oq][jo] = acc;
    __syncthreads();
    if (tid < 64)
        pooled[b * HIDN + jh * 64 + tid] =
            ((ps[0][tid] + ps[1][tid]) + (ps[2][tid] + ps[3][tid])) * (1.f / 6144.f);
}

// Out-GEMM tail, numerically identical to the old fused tail.
__global__ __launch_bounds__(256) void out_gemm_kernel(
    const float* __restrict__ pooled, const float* __restrict__ W_out,
    const float* __restrict__ b_out, float* __restrict__ out)
{
    const int b = blockIdx.x, tid = threadIdx.x;
    __shared__ float pooled_s[HIDN];
    if (tid < HIDN) pooled_s[tid] = pooled[b * HIDN + tid];
    __syncthreads();

    for (int o = tid; o < OUTN; o += 256) {
        float a = b_out[o];
#pragma unroll 8
        for (int k = 0; k < HIDN; k += 4) {
            float4 wv = *(const float4*)(W_out + o * HIDN + k);
            float4 pv = *(const float4*)&pooled_s[k];   // broadcast b128
            a += wv.x * pv.x + wv.y * pv.y + wv.z * pv.z + wv.w * pv.w;
        }
        out[b * OUTN + o] = a;
    }
}

extern "C" void kernel_launch(void* const* d_in, const int* in_sizes, int n_in,
                              void* d_out, int out_size, void* d_ws, size_t ws_size,
                              hipStream_t stream)
{
    const float* x     = (const float*)d_in[0];
    const float* h0    = (const float*)d_in[1];
    const float* W_in  = (const float*)d_in[2];
    const float* b_in  = (const float*)d_in[3];
    const float* W_ih  = (const float*)d_in[4];
    const float* b_ih  = (const float*)d_in[5];
    const float* W_hh  = (const float*)d_in[6];
    const float* b_hh  = (const float*)d_in[7];
    const float* W_out = (const float*)d_in[8];
    const float* b_out = (const float*)d_in[9];
    float* out = (float*)d_out;

    char* wsb = (char*)d_ws;
    unsigned short* hsb = (unsigned short*)wsb;
    float* pooled       = (float*)(wsb + 33554432);

    rnn_kernel<<<32, 512, 0, stream>>>(x, h0, W_in, b_in, W_ih, b_ih,
                                       W_hh, b_hh, hsb);
    pool_kernel<<<1024, 256, 0, stream>>>(hsb, pooled);
    out_gemm_kernel<<<512, 256, 0, stream>>>(pooled, W_out, b_out, out);
}

// Round 9
// 208.339 us; speedup vs baseline: 1.0417x; 1.0417x over previous
//
#include <hip/hip_runtime.h>

#define L 256
#define BATCH 512
#define CIN 32
#define HIDN 128
#define OUTN 512

typedef _Float16 f16x8 __attribute__((ext_vector_type(8)));
typedef float f32x4 __attribute__((ext_vector_type(4)));

#define MFMA16(a, b, c) __builtin_amdgcn_mfma_f32_16x16x32_f16(a, b, c, 0, 0, 0)

static __device__ __forceinline__ unsigned short f16b(_Float16 h) {
    unsigned short u; __builtin_memcpy(&u, &h, 2); return u;
}

// ws layout (bytes):
//   hs      @ 0        (33554432)  fp16 hs[b*32768 + t*128 + j]
//   pooledH @ 33554432 (131072)    fp16 hi of pooled[b*128 + j]
//   pooledL @ 33685504 (131072)    fp16 lo residual
//
// R18: single-variable experiment — rnn and pool are BYTE-IDENTICAL to R17.
// The ~97us residual (constant R0-R17, untouched by R17's pool restructure)
// is attributed to the out-GEMM's W_out read pattern: lane-consecutive o x
// 512B row stride = 64 distinct cache lines PER load instr, 2 MB/CU scattered
// L2 gather, 128 MB chip-wide re-read of a 256 KB matrix. Replaced with an
// MFMA GEMM (rnn-validated fragment machinery): W_out read ONCE (4 MB total),
// pooled passed as f16 hi/lo, 3-term product keeps error ~1e-6.

// MFMA RNN, fp16 2-term split. 32 blocks (16 batch rows) x 512 thr (8 waves,
// 2/SIMD). R16 structure frozen: 4-chain MFMA STEP, prep fused in prologue,
// ^tq staging swizzle, lgkmcnt(1) barrier guard w/ xB register prefetch.
__global__ __launch_bounds__(512, 1) void rnn_kernel(
    const float* __restrict__ x, const float* __restrict__ h0,
    const float* __restrict__ W_in, const float* __restrict__ b_in,
    const float* __restrict__ W_ih, const float* __restrict__ b_ih,
    const float* __restrict__ W_hh, const float* __restrict__ b_hh,
    unsigned short* __restrict__ hs)
{
    const int tid = threadIdx.x;
    const int bb = blockIdx.x;
    const int lane = tid & 63;
    const int w = tid >> 6;       // wave 0..7
    const int n = lane & 15;      // batch col / B col
    const int q = lane >> 4;      // quad

    __shared__ unsigned short hbuf[2][16][HIDN];     // 8 KB, granule swizzle ^(n&7)
    __shared__ unsigned short xcl[2][16][64][8];     // 32 KB, [buf][tt][granule][c&7]
    __shared__ float wih_s[128][65];                 // 33.3 KB, +1 pad: banks j+m
    __shared__ float win_s[64][32];                  // 8 KB
    __shared__ float bin_s[64];

    // ---- x chunk staging over 512 threads: i=tid+r*512 -> (nn,cc,tq) ----
    float4 xr[4];
    auto issue_chunk = [&](int ci) {
#pragma unroll
        for (int r = 0; r < 4; ++r) {
            int i = tid + r * 512;
            int nn = i >> 7, cc = (i >> 2) & 31, tq = i & 3;
            xr[r] = *(const float4*)(x + (((size_t)bb * 16 + nn) * CIN + cc) * L + ci * 16 + tq * 4);
        }
    };
    auto write_chunk = [&](int buf) {
#pragma unroll
        for (int r = 0; r < 4; ++r) {
            int i = tid + r * 512;
            int nn = i >> 7, cc = (i >> 2) & 31, tq = i & 3;
            int gr = ((cc >> 3) * 16 + (nn ^ ((cc >> 3) << 2))) ^ tq;  // ^tq: bank-spread
            float vv[4] = {xr[r].x, xr[r].y, xr[r].z, xr[r].w};
#pragma unroll
            for (int k = 0; k < 4; ++k)
                xcl[buf][tq * 4 + k][gr][cc & 7] = f16b((_Float16)vv[k]);
        }
    };

    issue_chunk(0);                       // x loads in flight over the prologue

    // ---- stage small weights to LDS ----
    for (int i = tid; i < 128 * 64; i += 512) wih_s[i >> 6][i & 63] = W_ih[i];
    for (int i = tid; i < 64 * 32; i += 512) ((float*)win_s)[i] = W_in[i];
    if (tid < 64) bin_s[tid] = b_in[tid];

    // ---- h0 -> fp16 plane, dbuf 0 (first 256 threads) ----
    if (tid < 256) {
        const int ni = tid >> 4, gi = tid & 15;
        const float4* src = (const float4*)(h0 + ((size_t)bb * 16 + ni) * HIDN + gi * 8);
        float4 a = src[0], b4 = src[1];
        float vv[8] = {a.x, a.y, a.z, a.w, b4.x, b4.y, b4.z, b4.w};
        unsigned short o[8];
#pragma unroll
        for (int i = 0; i < 8; ++i) o[i] = f16b((_Float16)vv[i]);
        *(uint4*)&hbuf[0][ni][(gi ^ (ni & 7)) * 8] = *(uint4*)o;
    }
    __syncthreads();

    // ---- prologue weight derivation (same FLOP order as old prep_kernel;
    //      verified bit-identical in R15/R16) ----
    const int jr = w * 16 + n;
    f16x8 Ah[4], Al[4];
    const float* wrow = W_hh + jr * HIDN;
#pragma unroll
    for (int kc = 0; kc < 4; ++kc) {
        float4 v0 = *(const float4*)(wrow + kc * 32 + q * 8);
        float4 v1 = *(const float4*)(wrow + kc * 32 + q * 8 + 4);
        float vv[8] = {v0.x, v0.y, v0.z, v0.w, v1.x, v1.y, v1.z, v1.w};
        f16x8 H, Lo;
#pragma unroll
        for (int i = 0; i < 8; ++i) {
            _Float16 hi = (_Float16)vv[i];
            H[i] = hi;
            Lo[i] = (_Float16)(vv[i] - (float)hi);
        }
        Ah[kc] = H; Al[kc] = Lo;
    }
    float acc8[8];
#pragma unroll
    for (int i = 0; i < 8; ++i) acc8[i] = 0.f;
    for (int m = 0; m < 64; ++m) {
        float wv = wih_s[jr][m];                 // pad-65 rows: conflict-free
        const float* wc = &win_s[m][q * 8];
#pragma unroll
        for (int i = 0; i < 8; ++i) acc8[i] += wv * wc[i];
    }
    f16x8 Axh, Axl;
#pragma unroll
    for (int i = 0; i < 8; ++i) {
        _Float16 hi = (_Float16)acc8[i];
        Axh[i] = hi;
        Axl[i] = (_Float16)(acc8[i] - (float)hi);
    }
    const int jb0 = w * 16 + q * 4;
    float bs4[4];
#pragma unroll
    for (int r = 0; r < 4; ++r) bs4[r] = b_ih[jb0 + r] + b_hh[jb0 + r];
    for (int m = 0; m < 64; ++m) {
        float bm = bin_s[m];
#pragma unroll
        for (int r = 0; r < 4; ++r) bs4[r] += wih_s[jb0 + r][m] * bm;
    }
    f32x4 bp = (f32x4){bs4[0], bs4[1], bs4[2], bs4[3]};
    const f32x4 zero4 = (f32x4){0.f, 0.f, 0.f, 0.f};

    // ---- finish x staging ----
    write_chunk(0);
    issue_chunk(1);
    __syncthreads();

    // hs [b][t][j]: pool reads each b-row as one sequential 64-KB stream.
    unsigned short* hsp = hs + ((size_t)bb * 16 + n) * (L * HIDN) + w * 16 + q * 4;
    const int G = (w * 2 + (q >> 1)) ^ (n & 7);
    const int sw = n & 7;
    const int grs = q * 16 + (n ^ (q << 2));   // this lane's xc granule (pre-swz)

    f16x8 xb0, xb1;
    xb0 = *(const f16x8*)&xcl[0][0][grs][0];   // t=0: tt>>2 = 0

#define STEP(T, IN, OUT, OFF, XCUR, XNEXT)                                     \
    {                                                                          \
        f16x8 Bh0 = *(const f16x8*)&hbuf[IN][n][((0 + q) ^ sw) * 8];           \
        f16x8 Bh1 = *(const f16x8*)&hbuf[IN][n][((4 + q) ^ sw) * 8];           \
        f16x8 Bh2 = *(const f16x8*)&hbuf[IN][n][((8 + q) ^ sw) * 8];           \
        f16x8 Bh3 = *(const f16x8*)&hbuf[IN][n][((12 + q) ^ sw) * 8];          \
        f32x4 c0 = MFMA16(Axh, XCUR, bp);      /* operands all in regs */      \
        f32x4 c2 = MFMA16(Axl, XCUR, zero4);                                   \
        c0 = MFMA16(Ah[0], Bh0, c0);                                           \
        c2 = MFMA16(Al[0], Bh0, c2);                                           \
        f32x4 c1 = MFMA16(Ah[1], Bh1, zero4);                                  \
        f32x4 c3 = MFMA16(Al[1], Bh1, zero4);                                  \
        c0 = MFMA16(Ah[2], Bh2, c0);                                           \
        c2 = MFMA16(Al[2], Bh2, c2);                                           \
        c1 = MFMA16(Ah[3], Bh3, c1);                                           \
        c3 = MFMA16(Al[3], Bh3, c3);                                           \
        if (((T) & 15) == 14 && (T) < L - 16) {                                \
            write_chunk((((T) >> 4) & 1) ^ 1);                                 \
            if ((T) < L - 32) issue_chunk(((T) >> 4) + 2);                     \
        }                                                                      \
        f32x4 acc = (c0 + c1) + (c2 + c3);                                     \
        unsigned short o[4];                                                   \
        for (int r = 0; r < 4; ++r) {                                          \
            float e = __expf(2.f * acc[r]);                                    \
            float hv = 1.f - 2.f * __builtin_amdgcn_rcpf(e + 1.f);             \
            o[r] = f16b((_Float16)hv);                                         \
        }                                                                      \
        uint2 pk; __builtin_memcpy(&pk, o, 8);                                 \
        *(uint2*)&hbuf[OUT][n][G * 8 + (q & 1) * 4] = pk;                      \
        *(uint2*)(hsp + (OFF)) = pk;                                           \
        XNEXT = *(const f16x8*)&xcl[(((T) + 1) >> 4) & 1][((T) + 1) & 15]      \
                                  [grs ^ ((((T) + 1) & 15) >> 2)][0];          \
        asm volatile("" ::: "memory");                                         \
        __builtin_amdgcn_s_waitcnt(0xC17F);  /* lgkmcnt(1): writes drained, */ \
        __builtin_amdgcn_s_barrier();        /* xB prefetch stays in flight */ \
        asm volatile("" ::: "memory");                                         \
    }

    for (int t = 0; t < L; t += 2) {
        STEP(t,     0, 1, 0,     xb0, xb1);
        STEP(t + 1, 1, 0, HIDN,  xb1, xb0);
        hsp += 2 * HIDN;
    }
#undef STEP
}

// Upsample(16->32, align_corners) + hardswish + mean. 1024 blocks = (b,
// j-half), 256 threads. Identical to R17 except the output: pooled emitted as
// f16 hi/lo pairs for the MFMA out-GEMM (H + L carries ~22 bits).
__global__ __launch_bounds__(256) void pool_kernel(
    const unsigned short* __restrict__ hs,
    unsigned short* __restrict__ pooledH, unsigned short* __restrict__ pooledL)
{
    const int b = blockIdx.x >> 1, jh = blockIdx.x & 1;
    const int tid = threadIdx.x;
    __shared__ unsigned short m[L][72];     // [t][j-local], pad 72 (144B rows, 16B-aligned)
    __shared__ float ps[4][64];

    const unsigned short* src = hs + (size_t)b * (L * HIDN) + jh * 64;
#pragma unroll
    for (int it = 0; it < 8; ++it) {
        int i = tid + it * 256;             // 256 t x 8 j-octets
        int t = i >> 3, joc = i & 7;
        *(uint4*)&m[t][joc * 8] = *(const uint4*)(src + t * HIDN + joc * 8);
    }
    __syncthreads();

    const int jo = tid & 63, oq = tid >> 6;
    float acc = 0.f;
    for (int oy = oq * 8; oy < oq * 8 + 8; ++oy) {
        float ysf = oy * (15.f / 31.f);
        int y0 = (int)ysf; float wy = ysf - (float)y0; int y1 = min(y0 + 1, 15);
        float rb[16];
#pragma unroll
        for (int sx = 0; sx < 16; ++sx) {
            float v0 = (float)*(const _Float16*)&m[y0 * 16 + sx][jo];
            float v1 = (float)*(const _Float16*)&m[y1 * 16 + sx][jo];
            rb[sx] = v0 + wy * (v1 - v0);
        }
#pragma unroll
        for (int ox = 0; ox < 32; ++ox) {
            float xsf = ox * (15.f / 31.f);
            int x0 = (int)xsf; float wx = xsf - (float)x0; int x1 = min(x0 + 1, 15);
            float v = rb[x0] + wx * (rb[x1] - rb[x0]);
            float t6 = fminf(fmaxf(v + 3.f, 0.f), 6.f);
            acc += v * t6;
        }
    }
    ps[oq][jo] = acc;
    __syncthreads();
    if (tid < 64) {
        float p = ((ps[0][tid] + ps[1][tid]) + (ps[2][tid] + ps[3][tid])) * (1.f / 6144.f);
        _Float16 H = (_Float16)p;
        _Float16 Lo = (_Float16)(p - (float)H);
        pooledH[b * HIDN + jh * 64 + tid] = f16b(H);
        pooledL[b * HIDN + jh * 64 + tid] = f16b(Lo);
    }
}

// MFMA out-GEMM: out[512b,512o] = pooled @ W_out^T + b_out.
// 64 blocks = (bg 16) x (oq 4); block = 32 b x 128 o; 8 waves = (bsub 2) x
// (osub 4); wave = 16 b x 32 o = 2 MFMA tiles, K=128. W_out read ONCE,
// per-lane hi/lo split (rnn-Whh-prologue pattern). 3-term product:
// Ah*Bh + Ah*Bl + Al*Bh (|Al*Bl| ~ 7e-7 dropped).
__global__ __launch_bounds__(512, 1) void out_gemm_kernel(
    const unsigned short* __restrict__ pooledH,
    const unsigned short* __restrict__ pooledL,
    const float* __restrict__ W_out, const float* __restrict__ b_out,
    float* __restrict__ out)
{
    const int tid = threadIdx.x;
    const int bg = blockIdx.x >> 2, oqd = blockIdx.x & 3;
    const int lane = tid & 63;
    const int w = tid >> 6;
    const int bsub = w & 1, osub = w >> 1;
    const int n = lane & 15;          // = MFMA A-row m and B-col n
    const int q = lane >> 4;

    const int bBase = bg * 32 + bsub * 16;
    const int oBase = oqd * 128 + osub * 32;

    // A-frags: W_out rows o = oBase + tile*16 + n, hi/lo split
    f16x8 Ah[2][4], Al[2][4];
#pragma unroll
    for (int tile = 0; tile < 2; ++tile) {
        const float* wrow = W_out + (oBase + tile * 16 + n) * HIDN;
#pragma unroll
        for (int kc = 0; kc < 4; ++kc) {
            float4 v0 = *(const float4*)(wrow + kc * 32 + q * 8);
            float4 v1 = *(const float4*)(wrow + kc * 32 + q * 8 + 4);
            float vv[8] = {v0.x, v0.y, v0.z, v0.w, v1.x, v1.y, v1.z, v1.w};
            f16x8 H, Lo;
#pragma unroll
            for (int i = 0; i < 8; ++i) {
                _Float16 hi = (_Float16)vv[i];
                H[i] = hi;
                Lo[i] = (_Float16)(vv[i] - (float)hi);
            }
            Ah[tile][kc] = H; Al[tile][kc] = Lo;
        }
    }
    // B-frags: pooled hi/lo, col n = b
    f16x8 Bh[4], Bl[4];
#pragma unroll
    for (int kc = 0; kc < 4; ++kc) {
        Bh[kc] = *(const f16x8*)(pooledH + (bBase + n) * HIDN + kc * 32 + q * 8);
        Bl[kc] = *(const f16x8*)(pooledL + (bBase + n) * HIDN + kc * 32 + q * 8);
    }
    const f32x4 zero4 = (f32x4){0.f, 0.f, 0.f, 0.f};

#pragma unroll
    for (int tile = 0; tile < 2; ++tile) {
        float4 bv = *(const float4*)(b_out + oBase + tile * 16 + q * 4);
        f32x4 aHH = (f32x4){bv.x, bv.y, bv.z, bv.w};
        f32x4 aHL = zero4, aLH = zero4;
#pragma unroll
        for (int kc = 0; kc < 4; ++kc) {
            aHH = MFMA16(Ah[tile][kc], Bh[kc], aHH);
            aHL = MFMA16(Ah[tile][kc], Bl[kc], aHL);
            aLH = MFMA16(Al[tile][kc], Bh[kc], aLH);
        }
        f32x4 acc = aHH + (aHL + aLH);
        // D rows = o = oBase + tile*16 + q*4 + r, col = b = bBase + n
        *(float4*)(out + (size_t)(bBase + n) * OUTN + oBase + tile * 16 + q * 4) =
            *(float4*)&acc;
    }
}

extern "C" void kernel_launch(void* const* d_in, const int* in_sizes, int n_in,
                              void* d_out, int out_size, void* d_ws, size_t ws_size,
                              hipStream_t stream)
{
    const float* x     = (const float*)d_in[0];
    const float* h0    = (const float*)d_in[1];
    const float* W_in  = (const float*)d_in[2];
    const float* b_in  = (const float*)d_in[3];
    const float* W_ih  = (const float*)d_in[4];
    const float* b_ih  = (const float*)d_in[5];
    const float* W_hh  = (const float*)d_in[6];
    const float* b_hh  = (const float*)d_in[7];
    const float* W_out = (const float*)d_in[8];
    const float* b_out = (const float*)d_in[9];
    float* out = (float*)d_out;

    char* wsb = (char*)d_ws;
    unsigned short* hsb     = (unsigned short*)wsb;
    unsigned short* pooledH = (unsigned short*)(wsb + 33554432);
    unsigned short* pooledL = (unsigned short*)(wsb + 33685504);

    rnn_kernel<<<32, 512, 0, stream>>>(x, h0, W_in, b_in, W_ih, b_ih,
                                       W_hh, b_hh, hsb);
    pool_kernel<<<1024, 256, 0, stream>>>(hsb, pooledH, pooledL);
    out_gemm_kernel<<<64, 512, 0, stream>>>(pooledH, pooledL, W_out, b_out, out);
}

// Round 10
// 207.393 us; speedup vs baseline: 1.0465x; 1.0046x over previous
//
#include <hip/hip_runtime.h>

#define L 256
#define BATCH 512
#define CIN 32
#define HIDN 128
#define OUTN 512

typedef _Float16 f16x8 __attribute__((ext_vector_type(8)));
typedef float f32x4 __attribute__((ext_vector_type(4)));

#define MFMA16(a, b, c) __builtin_amdgcn_mfma_f32_16x16x32_f16(a, b, c, 0, 0, 0)

static __device__ __forceinline__ unsigned short f16b(_Float16 h) {
    unsigned short u; __builtin_memcpy(&u, &h, 2); return u;
}

// ws layout (bytes):
//   hs      @ 0        (33554432)  fp16 hs[b*32768 + t*128 + j]
//   pooledH @ 33554432 (131072)    fp16 hi of pooled[b*128 + j]
//   pooledL @ 33685504 (131072)    fp16 lo residual
//
// R19: single-variable probe. R16/R17/R18 proved the non-rnn residual
// (~93us) is invariant to pool layout, pool occupancy, and gemm algorithm.
// The shared physical element is the 32MB hs round-trip: rnn leaves hs dirty
// across the 8 per-XCD L2s (32MB dirty = exactly 8x4MB); pool blocks on
// other XCDs then read remote-dirty lines — the non-coherent cross-XCD path.
// Fix attempt: XCD-affinity swizzle — pool block i serves a batch row
// produced by rnn block bb ≡ i (mod 8) (dispatch round-robin heuristic), so
// reads hit the block's OWN L2. Both jh half-row blocks of a b also pair on
// one XCD (shared 128B lines fetched once). rnn and gemm BYTE-IDENTICAL to
// R18; numerics bit-identical (pure index permutation).

// MFMA RNN, fp16 2-term split. 32 blocks (16 batch rows) x 512 thr (8 waves,
// 2/SIMD). R16 structure frozen: 4-chain MFMA STEP, prep fused in prologue,
// ^tq staging swizzle, lgkmcnt(1) barrier guard w/ xB register prefetch.
__global__ __launch_bounds__(512, 1) void rnn_kernel(
    const float* __restrict__ x, const float* __restrict__ h0,
    const float* __restrict__ W_in, const float* __restrict__ b_in,
    const float* __restrict__ W_ih, const float* __restrict__ b_ih,
    const float* __restrict__ W_hh, const float* __restrict__ b_hh,
    unsigned short* __restrict__ hs)
{
    const int tid = threadIdx.x;
    const int bb = blockIdx.x;
    const int lane = tid & 63;
    const int w = tid >> 6;       // wave 0..7
    const int n = lane & 15;      // batch col / B col
    const int q = lane >> 4;      // quad

    __shared__ unsigned short hbuf[2][16][HIDN];     // 8 KB, granule swizzle ^(n&7)
    __shared__ unsigned short xcl[2][16][64][8];     // 32 KB, [buf][tt][granule][c&7]
    __shared__ float wih_s[128][65];                 // 33.3 KB, +1 pad: banks j+m
    __shared__ float win_s[64][32];                  // 8 KB
    __shared__ float bin_s[64];

    // ---- x chunk staging over 512 threads: i=tid+r*512 -> (nn,cc,tq) ----
    float4 xr[4];
    auto issue_chunk = [&](int ci) {
#pragma unroll
        for (int r = 0; r < 4; ++r) {
            int i = tid + r * 512;
            int nn = i >> 7, cc = (i >> 2) & 31, tq = i & 3;
            xr[r] = *(const float4*)(x + (((size_t)bb * 16 + nn) * CIN + cc) * L + ci * 16 + tq * 4);
        }
    };
    auto write_chunk = [&](int buf) {
#pragma unroll
        for (int r = 0; r < 4; ++r) {
            int i = tid + r * 512;
            int nn = i >> 7, cc = (i >> 2) & 31, tq = i & 3;
            int gr = ((cc >> 3) * 16 + (nn ^ ((cc >> 3) << 2))) ^ tq;  // ^tq: bank-spread
            float vv[4] = {xr[r].x, xr[r].y, xr[r].z, xr[r].w};
#pragma unroll
            for (int k = 0; k < 4; ++k)
                xcl[buf][tq * 4 + k][gr][cc & 7] = f16b((_Float16)vv[k]);
        }
    };

    issue_chunk(0);                       // x loads in flight over the prologue

    // ---- stage small weights to LDS ----
    for (int i = tid; i < 128 * 64; i += 512) wih_s[i >> 6][i & 63] = W_ih[i];
    for (int i = tid; i < 64 * 32; i += 512) ((float*)win_s)[i] = W_in[i];
    if (tid < 64) bin_s[tid] = b_in[tid];

    // ---- h0 -> fp16 plane, dbuf 0 (first 256 threads) ----
    if (tid < 256) {
        const int ni = tid >> 4, gi = tid & 15;
        const float4* src = (const float4*)(h0 + ((size_t)bb * 16 + ni) * HIDN + gi * 8);
        float4 a = src[0], b4 = src[1];
        float vv[8] = {a.x, a.y, a.z, a.w, b4.x, b4.y, b4.z, b4.w};
        unsigned short o[8];
#pragma unroll
        for (int i = 0; i < 8; ++i) o[i] = f16b((_Float16)vv[i]);
        *(uint4*)&hbuf[0][ni][(gi ^ (ni & 7)) * 8] = *(uint4*)o;
    }
    __syncthreads();

    // ---- prologue weight derivation (same FLOP order as old prep_kernel;
    //      verified bit-identical in R15/R16) ----
    const int jr = w * 16 + n;
    f16x8 Ah[4], Al[4];
    const float* wrow = W_hh + jr * HIDN;
#pragma unroll
    for (int kc = 0; kc < 4; ++kc) {
        float4 v0 = *(const float4*)(wrow + kc * 32 + q * 8);
        float4 v1 = *(const float4*)(wrow + kc * 32 + q * 8 + 4);
        float vv[8] = {v0.x, v0.y, v0.z, v0.w, v1.x, v1.y, v1.z, v1.w};
        f16x8 H, Lo;
#pragma unroll
        for (int i = 0; i < 8; ++i) {
            _Float16 hi = (_Float16)vv[i];
            H[i] = hi;
            Lo[i] = (_Float16)(vv[i] - (float)hi);
        }
        Ah[kc] = H; Al[kc] = Lo;
    }
    float acc8[8];
#pragma unroll
    for (int i = 0; i < 8; ++i) acc8[i] = 0.f;
    for (int m = 0; m < 64; ++m) {
        float wv = wih_s[jr][m];                 // pad-65 rows: conflict-free
        const float* wc = &win_s[m][q * 8];
#pragma unroll
        for (int i = 0; i < 8; ++i) acc8[i] += wv * wc[i];
    }
    f16x8 Axh, Axl;
#pragma unroll
    for (int i = 0; i < 8; ++i) {
        _Float16 hi = (_Float16)acc8[i];
        Axh[i] = hi;
        Axl[i] = (_Float16)(acc8[i] - (float)hi);
    }
    const int jb0 = w * 16 + q * 4;
    float bs4[4];
#pragma unroll
    for (int r = 0; r < 4; ++r) bs4[r] = b_ih[jb0 + r] + b_hh[jb0 + r];
    for (int m = 0; m < 64; ++m) {
        float bm = bin_s[m];
#pragma unroll
        for (int r = 0; r < 4; ++r) bs4[r] += wih_s[jb0 + r][m] * bm;
    }
    f32x4 bp = (f32x4){bs4[0], bs4[1], bs4[2], bs4[3]};
    const f32x4 zero4 = (f32x4){0.f, 0.f, 0.f, 0.f};

    // ---- finish x staging ----
    write_chunk(0);
    issue_chunk(1);
    __syncthreads();

    // hs [b][t][j]: pool reads each b-row as one sequential 64-KB stream.
    unsigned short* hsp = hs + ((size_t)bb * 16 + n) * (L * HIDN) + w * 16 + q * 4;
    const int G = (w * 2 + (q >> 1)) ^ (n & 7);
    const int sw = n & 7;
    const int grs = q * 16 + (n ^ (q << 2));   // this lane's xc granule (pre-swz)

    f16x8 xb0, xb1;
    xb0 = *(const f16x8*)&xcl[0][0][grs][0];   // t=0: tt>>2 = 0

#define STEP(T, IN, OUT, OFF, XCUR, XNEXT)                                     \
    {                                                                          \
        f16x8 Bh0 = *(const f16x8*)&hbuf[IN][n][((0 + q) ^ sw) * 8];           \
        f16x8 Bh1 = *(const f16x8*)&hbuf[IN][n][((4 + q) ^ sw) * 8];           \
        f16x8 Bh2 = *(const f16x8*)&hbuf[IN][n][((8 + q) ^ sw) * 8];           \
        f16x8 Bh3 = *(const f16x8*)&hbuf[IN][n][((12 + q) ^ sw) * 8];          \
        f32x4 c0 = MFMA16(Axh, XCUR, bp);      /* operands all in regs */      \
        f32x4 c2 = MFMA16(Axl, XCUR, zero4);                                   \
        c0 = MFMA16(Ah[0], Bh0, c0);                                           \
        c2 = MFMA16(Al[0], Bh0, c2);                                           \
        f32x4 c1 = MFMA16(Ah[1], Bh1, zero4);                                  \
        f32x4 c3 = MFMA16(Al[1], Bh1, zero4);                                  \
        c0 = MFMA16(Ah[2], Bh2, c0);                                           \
        c2 = MFMA16(Al[2], Bh2, c2);                                           \
        c1 = MFMA16(Ah[3], Bh3, c1);                                           \
        c3 = MFMA16(Al[3], Bh3, c3);                                           \
        if (((T) & 15) == 14 && (T) < L - 16) {                                \
            write_chunk((((T) >> 4) & 1) ^ 1);                                 \
            if ((T) < L - 32) issue_chunk(((T) >> 4) + 2);                     \
        }                                                                      \
        f32x4 acc = (c0 + c1) + (c2 + c3);                                     \
        unsigned short o[4];                                                   \
        for (int r = 0; r < 4; ++r) {                                          \
            float e = __expf(2.f * acc[r]);                                    \
            float hv = 1.f - 2.f * __builtin_amdgcn_rcpf(e + 1.f);             \
            o[r] = f16b((_Float16)hv);                                         \
        }                                                                      \
        uint2 pk; __builtin_memcpy(&pk, o, 8);                                 \
        *(uint2*)&hbuf[OUT][n][G * 8 + (q & 1) * 4] = pk;                      \
        *(uint2*)(hsp + (OFF)) = pk;                                           \
        XNEXT = *(const f16x8*)&xcl[(((T) + 1) >> 4) & 1][((T) + 1) & 15]      \
                                  [grs ^ ((((T) + 1) & 15) >> 2)][0];          \
        asm volatile("" ::: "memory");                                         \
        __builtin_amdgcn_s_waitcnt(0xC17F);  /* lgkmcnt(1): writes drained, */ \
        __builtin_amdgcn_s_barrier();        /* xB prefetch stays in flight */ \
        asm volatile("" ::: "memory");                                         \
    }

    for (int t = 0; t < L; t += 2) {
        STEP(t,     0, 1, 0,     xb0, xb1);
        STEP(t + 1, 1, 0, HIDN,  xb1, xb0);
        hsp += 2 * HIDN;
    }
#undef STEP
}

// Upsample(16->32, align_corners) + hardswish + mean. 1024 blocks, 256 thr.
// R19: XCD-affinity block swizzle — block i serves (b, jh) produced by rnn
// block bb = (i&7) + 8*((i>>3)&3), i.e. bb ≡ i (mod 8) so (under round-robin
// dispatch) this block's XCD is where hs[b] was written. Both jh blocks of a
// b pair on the same XCD -> shared 128B lines fetched once into that L2.
// Work/addressing otherwise identical to R17/R18.
__global__ __launch_bounds__(256) void pool_kernel(
    const unsigned short* __restrict__ hs,
    unsigned short* __restrict__ pooledH, unsigned short* __restrict__ pooledL)
{
    const int i = blockIdx.x;
    const int k = i & 7, s = i >> 3;           // k: target XCD residue
    const int bb = k + 8 * (s & 3);            // producer rnn block (same XCD)
    const int inner = s >> 2;                  // 0..31: 16 b-rows x 2 jh
    const int b = bb * 16 + (inner >> 1), jh = inner & 1;
    const int tid = threadIdx.x;
    __shared__ unsigned short m[L][72];     // [t][j-local], pad 72
    __shared__ float ps[4][64];

    const unsigned short* src = hs + (size_t)b * (L * HIDN) + jh * 64;
#pragma unroll
    for (int it = 0; it < 8; ++it) {
        int ii = tid + it * 256;            // 256 t x 8 j-octets
        int t = ii >> 3, joc = ii & 7;
        *(uint4*)&m[t][joc * 8] = *(const uint4*)(src + t * HIDN + joc * 8);
    }
    __syncthreads();

    const int jo = tid & 63, oq = tid >> 6;
    float acc = 0.f;
    for (int oy = oq * 8; oy < oq * 8 + 8; ++oy) {
        float ysf = oy * (15.f / 31.f);
        int y0 = (int)ysf; float wy = ysf - (float)y0; int y1 = min(y0 + 1, 15);
        float rb[16];
#pragma unroll
        for (int sx = 0; sx < 16; ++sx) {
            float v0 = (float)*(const _Float16*)&m[y0 * 16 + sx][jo];
            float v1 = (float)*(const _Float16*)&m[y1 * 16 + sx][jo];
            rb[sx] = v0 + wy * (v1 - v0);
        }
#pragma unroll
        for (int ox = 0; ox < 32; ++ox) {
            float xsf = ox * (15.f / 31.f);
            int x0 = (int)xsf; float wx = xsf - (float)x0; int x1 = min(x0 + 1, 15);
            float v = rb[x0] + wx * (rb[x1] - rb[x0]);
            float t6 = fminf(fmaxf(v + 3.f, 0.f), 6.f);
            acc += v * t6;
        }
    }
    ps[oq][jo] = acc;
    __syncthreads();
    if (tid < 64) {
        float p = ((ps[0][tid] + ps[1][tid]) + (ps[2][tid] + ps[3][tid])) * (1.f / 6144.f);
        _Float16 H = (_Float16)p;
        _Float16 Lo = (_Float16)(p - (float)H);
        pooledH[b * HIDN + jh * 64 + tid] = f16b(H);
        pooledL[b * HIDN + jh * 64 + tid] = f16b(Lo);
    }
}

// MFMA out-GEMM: out[512b,512o] = pooled @ W_out^T + b_out. (R18, unchanged)
__global__ __launch_bounds__(512, 1) void out_gemm_kernel(
    const unsigned short* __restrict__ pooledH,
    const unsigned short* __restrict__ pooledL,
    const float* __restrict__ W_out, const float* __restrict__ b_out,
    float* __restrict__ out)
{
    const int tid = threadIdx.x;
    const int bg = blockIdx.x >> 2, oqd = blockIdx.x & 3;
    const int lane = tid & 63;
    const int w = tid >> 6;
    const int bsub = w & 1, osub = w >> 1;
    const int n = lane & 15;          // = MFMA A-row m and B-col n
    const int q = lane >> 4;

    const int bBase = bg * 32 + bsub * 16;
    const int oBase = oqd * 128 + osub * 32;

    f16x8 Ah[2][4], Al[2][4];
#pragma unroll
    for (int tile = 0; tile < 2; ++tile) {
        const float* wrow = W_out + (oBase + tile * 16 + n) * HIDN;
#pragma unroll
        for (int kc = 0; kc < 4; ++kc) {
            float4 v0 = *(const float4*)(wrow + kc * 32 + q * 8);
            float4 v1 = *(const float4*)(wrow + kc * 32 + q * 8 + 4);
            float vv[8] = {v0.x, v0.y, v0.z, v0.w, v1.x, v1.y, v1.z, v1.w};
            f16x8 H, Lo;
#pragma unroll
            for (int i = 0; i < 8; ++i) {
                _Float16 hi = (_Float16)vv[i];
                H[i] = hi;
                Lo[i] = (_Float16)(vv[i] - (float)hi);
            }
            Ah[tile][kc] = H; Al[tile][kc] = Lo;
        }
    }
    f16x8 Bh[4], Bl[4];
#pragma unroll
    for (int kc = 0; kc < 4; ++kc) {
        Bh[kc] = *(const f16x8*)(pooledH + (bBase + n) * HIDN + kc * 32 + q * 8);
        Bl[kc] = *(const f16x8*)(pooledL + (bBase + n) * HIDN + kc * 32 + q * 8);
    }
    const f32x4 zero4 = (f32x4){0.f, 0.f, 0.f, 0.f};

#pragma unroll
    for (int tile = 0; tile < 2; ++tile) {
        float4 bv = *(const float4*)(b_out + oBase + tile * 16 + q * 4);
        f32x4 aHH = (f32x4){bv.x, bv.y, bv.z, bv.w};
        f32x4 aHL = zero4, aLH = zero4;
#pragma unroll
        for (int kc = 0; kc < 4; ++kc) {
            aHH = MFMA16(Ah[tile][kc], Bh[kc], aHH);
            aHL = MFMA16(Ah[tile][kc], Bl[kc], aHL);
            aLH = MFMA16(Al[tile][kc], Bh[kc], aLH);
        }
        f32x4 acc = aHH + (aHL + aLH);
        *(float4*)(out + (size_t)(bBase + n) * OUTN + oBase + tile * 16 + q * 4) =
            *(float4*)&acc;
    }
}

extern "C" void kernel_launch(void* const* d_in, const int* in_sizes, int n_in,
                              void* d_out, int out_size, void* d_ws, size_t ws_size,
                              hipStream_t stream)
{
    const float* x     = (const float*)d_in[0];
    const float* h0    = (const float*)d_in[1];
    const float* W_in  = (const float*)d_in[2];
    const float* b_in  = (const float*)d_in[3];
    const float* W_ih  = (const float*)d_in[4];
    const float* b_ih  = (const float*)d_in[5];
    const float* W_hh  = (const float*)d_in[6];
    const float* b_hh  = (const float*)d_in[7];
    const float* W_out = (const float*)d_in[8];
    const float* b_out = (const float*)d_in[9];
    float* out = (float*)d_out;

    char* wsb = (char*)d_ws;
    unsigned short* hsb     = (unsigned short*)wsb;
    unsigned short* pooledH = (unsigned short*)(wsb + 33554432);
    unsigned short* pooledL = (unsigned short*)(wsb + 33685504);

    rnn_kernel<<<32, 512, 0, stream>>>(x, h0, W_in, b_in, W_ih, b_ih,
                                       W_hh, b_hh, hsb);
    pool_kernel<<<1024, 256, 0, stream>>>(hsb, pooledH, pooledL);
    out_gemm_kernel<<<64, 512, 0, stream>>>(pooledH, pooledL, W_out, b_out, out);
}